// Round 1
// baseline (84.274 us; speedup 1.0000x reference)
//
#include <hip/hip_runtime.h>
#include <math.h>

#define PATCHES 196
#define KPAD 800                 // 784 padded to 25*32 for MFMA K-loop
#define MROWS 8                  // batch rows per block
#define CIRC (MROWS * PATCHES)   // 1568 circuits per block
#define THREADS 512
#define FRAG_ELEMS (25 * 64 * 8) // full 16-row A-frag (rows 8..15 zeroed)

typedef short short8 __attribute__((ext_vector_type(8)));
typedef float f32x4 __attribute__((ext_vector_type(4)));
typedef float f2 __attribute__((ext_vector_type(2)));

__device__ __forceinline__ unsigned short f2bf(float f) {
  union { float f; unsigned u; } x; x.f = f;
  unsigned r = x.u + 0x7fff + ((x.u >> 16) & 1);  // round-to-nearest-even
  return (unsigned short)(r >> 16);
}

// ---------------------------------------------------------------------------
// Stage 0: pack W1^T (bf16, K zero-padded) into B-fragment order:
// elem = ntile*FRAG_ELEMS + (ki*64 + quad*16 + n15)*8 + j  (lane-contiguous)
// ---------------------------------------------------------------------------
__global__ __launch_bounds__(256) void w1t_pack_kernel(
    const float* __restrict__ W1, unsigned short* __restrict__ w1p) {
  int idx = blockIdx.x * 256 + threadIdx.x;
  if (idx >= 128 * KPAD) return;
  int n = idx / KPAD;
  int k = idx - n * KPAD;
  float v = (k < 784) ? W1[k * 128 + n] : 0.f;
  int ki = k >> 5;
  int quad = (k & 31) >> 3;
  int j = k & 7;
  w1p[(n >> 4) * FRAG_ELEMS + (ki * 64 + quad * 16 + (n & 15)) * 8 + j] = f2bf(v);
}

// ---------------------------------------------------------------------------
// Fused kernel (R12): R11 structure, but phase 1 is STRAIGHT-LINE with named
// f2 registers. R11's `#pragma unroll 1` loop indexed xA[jP]/xB[jP] with
// runtime jP -> the f2 arrays were unpromotable (SROA fails on runtime idx)
// and lived in SCRATCH (rule #20: ~5x slowdown). All indices are now
// compile-time. The 94%-invalid 4th circuit chain is predicated to tid<32
// (wave-uniform skip for waves 1..7), removing 23% of phase-1 VALU work.
// ---------------------------------------------------------------------------
__device__ __forceinline__ void ry_pair(f2& lo, f2& hi, float c, float s) {
  f2 a = lo, b = hi;
  lo = c * a - s * b;
  hi = s * a + c * b;
}
__device__ __forceinline__ f2 ry_in(f2 v, float c, float s) {
  f2 sw = v.yx;
  f2 ms = {-s, s};
  return c * v + ms * sw;
}

struct Meas { float m0, m1, m2, m3; };

__device__ __forceinline__ Meas run_circuit(f2 xa, f2 xb,
                                            const float (&tc)[8],
                                            const float (&tsn)[8]) {
  // product-state encoder
  float c0 = __cosf(0.5f * xa.x), s0 = __sinf(0.5f * xa.x);
  float c1 = __cosf(0.5f * xa.y), s1 = __sinf(0.5f * xa.y);
  float c2 = __cosf(0.5f * xb.x), s2 = __sinf(0.5f * xb.x);
  float c3 = __cosf(0.5f * xb.y), s3 = __sinf(0.5f * xb.y);
  float u00 = c0 * c1, u01 = c0 * s1, u10 = s0 * c1, u11 = s0 * s1;
  f2 wlo = {c2 * c3, c2 * s3};
  f2 whi = {s2 * c3, s2 * s3};

  f2 st2[8];
  st2[0] = u00 * wlo; st2[1] = u00 * whi;
  st2[2] = u01 * wlo; st2[3] = u01 * whi;
  st2[4] = u10 * wlo; st2[5] = u10 * whi;
  st2[6] = u11 * wlo; st2[7] = u11 * whi;

#pragma unroll
  for (int l = 0; l < 2; ++l) {
    const int b = l * 4;
    ry_pair(st2[0], st2[4], tc[b + 0], tsn[b + 0]);
    ry_pair(st2[1], st2[5], tc[b + 0], tsn[b + 0]);
    ry_pair(st2[2], st2[6], tc[b + 0], tsn[b + 0]);
    ry_pair(st2[3], st2[7], tc[b + 0], tsn[b + 0]);
    ry_pair(st2[0], st2[2], tc[b + 1], tsn[b + 1]);
    ry_pair(st2[1], st2[3], tc[b + 1], tsn[b + 1]);
    ry_pair(st2[4], st2[6], tc[b + 1], tsn[b + 1]);
    ry_pair(st2[5], st2[7], tc[b + 1], tsn[b + 1]);
    ry_pair(st2[0], st2[1], tc[b + 2], tsn[b + 2]);
    ry_pair(st2[2], st2[3], tc[b + 2], tsn[b + 2]);
    ry_pair(st2[4], st2[5], tc[b + 2], tsn[b + 2]);
    ry_pair(st2[6], st2[7], tc[b + 2], tsn[b + 2]);
#pragma unroll
    for (int k = 0; k < 8; ++k) st2[k] = ry_in(st2[k], tc[b + 3], tsn[b + 3]);
    // CNOT(0,1), CNOT(1,2): register renames
    { f2 t = st2[4]; st2[4] = st2[6]; st2[6] = t; }
    { f2 t = st2[5]; st2[5] = st2[7]; st2[7] = t; }
    { f2 t = st2[2]; st2[2] = st2[3]; st2[3] = t; }
    { f2 t = st2[6]; st2[6] = st2[7]; st2[7] = t; }
    // CNOT(2,3)
    st2[1] = st2[1].yx; st2[3] = st2[3].yx;
    st2[5] = st2[5].yx; st2[7] = st2[7].yx;
    // CNOT(3,0)
#pragma unroll
    for (int k = 0; k < 4; ++k) {
      f2 a = st2[k], bb = st2[k + 4];
      st2[k]     = (f2){a.x, bb.y};
      st2[k + 4] = (f2){bb.x, a.y};
    }
  }

  float h[8], d[8];
#pragma unroll
  for (int k = 0; k < 8; ++k) {
    f2 p2 = st2[k] * st2[k];
    h[k] = p2.x + p2.y;
    d[k] = p2.x - p2.y;
  }
  float a0 = h[0] + h[1], a1 = h[2] + h[3], a2 = h[4] + h[5], a3 = h[6] + h[7];
  float b0 = h[0] - h[1], b1 = h[2] - h[3], b2 = h[4] - h[5], b3 = h[6] - h[7];
  Meas r;
  r.m0 = (a0 + a1) - (a2 + a3);
  r.m1 = (a0 - a1) + (a2 - a3);
  r.m2 = (b0 + b1) + (b2 + b3);
  r.m3 = ((d[0] + d[1]) + (d[2] + d[3])) + ((d[4] + d[5]) + (d[6] + d[7]));
  return r;
}

__device__ __forceinline__ const float* xptr(const float* __restrict__ x,
                                             int row0, int c) {
  int bl = c / PATCHES;
  int p = c - bl * PATCHES;
  int pr = p / 14, pc = p - pr * 14;
  return x + (size_t)(row0 + bl) * 784 + pr * 56 + pc * 2;
}

__device__ __forceinline__ void store_meas(unsigned short* __restrict__ afr,
                                           int c, const Meas& M) {
  int bl = c / PATCHES;
  int p = c - bl * PATCHES;
  int K = p * 4;
  ushort4 o;
  o.x = f2bf(M.m0); o.y = f2bf(M.m1); o.z = f2bf(M.m2); o.w = f2bf(M.m3);
  *reinterpret_cast<ushort4*>(
      afr + ((K >> 5) * 64 + ((K & 31) >> 3) * 16 + bl) * 8 + (K & 7)) = o;
}

__global__ __launch_bounds__(THREADS) void fused_kernel(
    const float* __restrict__ x, const float* __restrict__ theta,
    const unsigned short* __restrict__ w1p, const float* __restrict__ b1,
    const float* __restrict__ W2, const float* __restrict__ b2,
    float* __restrict__ out) {
  __shared__ unsigned short afr[FRAG_ELEMS];   // 25.6 KB A tile, frag order
  __shared__ float ws2[1280];                  // W2 staged (5 KB)
  __shared__ float hs[MROWS * 132];
  __shared__ float ls[MROWS * 10];

  const int tid = threadIdx.x;
  const int lane = tid & 63;
  const int wave = tid >> 6;           // 0..7 = n-tile
  const int row0 = blockIdx.x * MROWS;

  // B-fragment prefetch: chunks 0..3 into registers (16 VGPR)
  const unsigned short* bp = w1p + (size_t)wave * FRAG_ELEMS + lane * 8;
  short8 bpf[4];
#pragma unroll
  for (int u = 0; u < 4; ++u)
    bpf[u] = *reinterpret_cast<const short8*>(bp + u * 512);

  // ---- phase 0: zero afr (K-pad + MFMA rows 8..15), stage W2 ----
  {
    ushort4 z; z.x = z.y = z.z = z.w = 0;
    for (int s = tid; s < FRAG_ELEMS / 4; s += THREADS)
      reinterpret_cast<ushort4*>(afr)[s] = z;
  }
  if (tid < 320)
    reinterpret_cast<float4*>(ws2)[tid] = reinterpret_cast<const float4*>(W2)[tid];

  // theta trig in registers (statically indexed)
  float tc[8], tsn[8];
#pragma unroll
  for (int w = 0; w < 8; ++w) {
    float a = 0.5f * theta[w];
    tc[w] = __cosf(a);
    tsn[w] = __sinf(a);
  }

  // preload x for all 4 circuit slots into NAMED registers (8 loads in flight;
  // no arrays -> nothing can be demoted to scratch)
  const float* p0 = xptr(x, row0, tid);
  const float* p1 = xptr(x, row0, tid + THREADS);
  const float* p2 = xptr(x, row0, tid + 2 * THREADS);
  int c3 = tid + 3 * THREADS;
  if (c3 >= CIRC) c3 = CIRC - 1;       // clamp: valid addr, result discarded
  const float* p3 = xptr(x, row0, c3);
  f2 x0a = *reinterpret_cast<const f2*>(p0);
  f2 x0b = *reinterpret_cast<const f2*>(p0 + 28);
  f2 x1a = *reinterpret_cast<const f2*>(p1);
  f2 x1b = *reinterpret_cast<const f2*>(p1 + 28);
  f2 x2a = *reinterpret_cast<const f2*>(p2);
  f2 x2b = *reinterpret_cast<const f2*>(p2 + 28);
  f2 x3a = *reinterpret_cast<const f2*>(p3);
  f2 x3b = *reinterpret_cast<const f2*>(p3 + 28);
  __syncthreads();

  // ---- phase 1: straight-line circuits, all indices compile-time ----
  {
    Meas M0 = run_circuit(x0a, x0b, tc, tsn);   // chains M0/M1 interleave (ILP)
    Meas M1 = run_circuit(x1a, x1b, tc, tsn);
    store_meas(afr, tid, M0);
    store_meas(afr, tid + THREADS, M1);
    Meas M2 = run_circuit(x2a, x2b, tc, tsn);
    if (tid < CIRC - 3 * THREADS) {             // tid < 32: only wave 0 diverges
      Meas M3 = run_circuit(x3a, x3b, tc, tsn);
      store_meas(afr, tid + 3 * THREADS, M3);
    }
    store_meas(afr, tid + 2 * THREADS, M2);
  }
  __syncthreads();

  // ---- phase 2: MFMA K-loop, all 8 waves (one n-tile each) ----
  const int m = lane & 15;
  const int quad = lane >> 4;

  {
    const unsigned short* apl = afr + lane * 8;
    f32x4 acc = {0.f, 0.f, 0.f, 0.f};

#pragma unroll
    for (int ki = 0; ki < 25; ++ki) {
      short8 a = *reinterpret_cast<const short8*>(apl + ki * 512);
      short8 b = (ki < 4) ? bpf[ki]
                          : *reinterpret_cast<const short8*>(bp + ki * 512);
      acc = __builtin_amdgcn_mfma_f32_16x16x32_bf16(a, b, acc, 0, 0, 0);
    }

    if (quad < 2) {
      const int col = wave * 16 + m;
      const float bc = b1[col];
#pragma unroll
      for (int r = 0; r < 4; ++r)
        hs[(quad * 4 + r) * 132 + col] = fmaxf(acc[r] + bc, 0.f);
    }
  }
  __syncthreads();

  // ---- GEMM2: 8 rows x 10 classes, W2 from LDS ----
  if (tid < MROWS * 10) {
    const int r = tid / 10;
    const int k = tid - r * 10;
    float a = b2[k];
    const float* hr = hs + r * 132;
#pragma unroll 8
    for (int jj = 0; jj < 128; ++jj) a = fmaf(hr[jj], ws2[jj * 10 + k], a);
    ls[tid] = a;
  }
  __syncthreads();

  // ---- log_softmax ----
  if (tid < MROWS) {
    const int r = tid;
    float mx = ls[r * 10];
#pragma unroll
    for (int k = 1; k < 10; ++k) mx = fmaxf(mx, ls[r * 10 + k]);
    float sum = 0.f;
#pragma unroll
    for (int k = 0; k < 10; ++k) sum += __expf(ls[r * 10 + k] - mx);
    const float lse = mx + __logf(sum);
    float* orow = out + (size_t)(row0 + r) * 10;
#pragma unroll
    for (int k = 0; k < 10; ++k) orow[k] = ls[r * 10 + k] - lse;
  }
}

extern "C" void kernel_launch(void* const* d_in, const int* in_sizes, int n_in,
                              void* d_out, int out_size, void* d_ws, size_t ws_size,
                              hipStream_t stream) {
  const float* x     = (const float*)d_in[0];
  const float* theta = (const float*)d_in[1];
  const float* W1    = (const float*)d_in[2];
  const float* b1    = (const float*)d_in[3];
  const float* W2    = (const float*)d_in[4];
  const float* b2    = (const float*)d_in[5];
  float* out = (float*)d_out;

  const int B = in_sizes[0] / 784;

  unsigned short* w1p = (unsigned short*)d_ws;   // 128*KPAD bf16 = 200 KB

  w1t_pack_kernel<<<(128 * KPAD + 255) / 256, 256, 0, stream>>>(W1, w1p);
  fused_kernel<<<B / MROWS, THREADS, 0, stream>>>(x, theta, w1p, b1, W2, b2, out);
}